// Round 22
// baseline (75.952 us; speedup 1.0000x reference)
//
#include <hip/hip_runtime.h>

#define E  1024
#define H  64
#define BB 8
#define TT 2048

typedef __attribute__((ext_vector_type(8)))  short bf16x8;
typedef __attribute__((ext_vector_type(4)))  float f32x4;
typedef __attribute__((ext_vector_type(16))) float f32x16;
typedef __attribute__((ext_vector_type(8)))  short short8;
typedef __attribute__((ext_vector_type(4)))  short short4v;
typedef __attribute__((ext_vector_type(4)))  unsigned u32x4;

__device__ __forceinline__ short f2bf(float f) {
    union { float f; unsigned u; } v; v.f = f;
    unsigned r = v.u + 0x7FFFu + ((v.u >> 16) & 1u);   // RNE
    return (short)(r >> 16);
}

// fast 2^x via the HW transcendental (no HIP __exp2f intrinsic exists)
__device__ __forceinline__ float fexp2(float x) {
    float r;
    asm("v_exp_f32 %0, %1" : "=v"(r) : "v"(x));
    return r;
}

__device__ __forceinline__ bf16x8 asbf(u32x4 v) {
    bf16x8 r;
    __builtin_memcpy(&r, &v, 16);
    return r;
}

// 8 fp32 (as 2x u32x4) -> bf16x8 via 4x v_cvt_pk_bf16_f32
__device__ __forceinline__ bf16x8 cvt8u(u32x4 a, u32x4 b) {
    unsigned w0, w1, w2, w3;
    float a0 = __uint_as_float(a[0]), a1 = __uint_as_float(a[1]);
    float a2 = __uint_as_float(a[2]), a3 = __uint_as_float(a[3]);
    float b0 = __uint_as_float(b[0]), b1 = __uint_as_float(b[1]);
    float b2 = __uint_as_float(b[2]), b3 = __uint_as_float(b[3]);
    asm("v_cvt_pk_bf16_f32 %0, %1, %2" : "=v"(w0) : "v"(a0), "v"(a1));
    asm("v_cvt_pk_bf16_f32 %0, %1, %2" : "=v"(w1) : "v"(a2), "v"(a3));
    asm("v_cvt_pk_bf16_f32 %0, %1, %2" : "=v"(w2) : "v"(b0), "v"(b1));
    asm("v_cvt_pk_bf16_f32 %0, %1, %2" : "=v"(w3) : "v"(b2), "v"(b3));
    u32x4 u = {w0, w1, w2, w3};
    return asbf(u);
}

// forced 16B global load: volatile asm with distinct "=v" outputs cannot be
// serialized by the register allocator
#define GLD(dst, p) \
    asm volatile("global_load_dwordx4 %0, %1, off" \
                 : "=v"(dst) : "v"((unsigned long long)(p)) : "memory")

// ---- pack W into per-K-step, frag-ordered CONTIGUOUS blocks (16x16x32 B) ----
__global__ __launch_bounds__(256)
void pack_w3(const float* __restrict__ Wq, const float* __restrict__ Wk,
             const float* __restrict__ Wv, short* __restrict__ Wb3)
{
    const int t  = blockIdx.x * 256 + threadIdx.x;   // 24576 total
    const int l  = t & 63;
    const int f  = (t >> 6) % 12;
    const int sc = t / 768;                          // k32-chunk 0..31
    const int n  = f * 16 + (l & 15);
    const int m  = n >> 6, nn = n & 63;
    const float* W = (m == 0) ? Wq : (m == 1 ? Wk : Wv);
    const int k0 = sc * 32 + ((l >> 4) << 3);
    short8 o;
    #pragma unroll
    for (int j = 0; j < 8; ++j) o[j] = f2bf(W[(k0 + j) * 64 + nn]);
    *(short8*)&Wb3[(size_t)t * 8] = o;
}

// ---- proj v14: asm pipeline (v13) x high TLP (v12). No LDS, no barriers ----
// 1024 blocks x 256 thr = 4 blocks/CU, 16 waves/CU, each wave INDEPENDENT:
// wave cg = 16 rows x 48 cols (3 frags, acc 12 VGPR). Per K32-step: 2 A +
// 3 B loads via asm GLD (named stage regs), 2-stage pipeline, vmcnt(5)
// keeps the next stage's 5 loads in flight. TLP (4 waves/EU) covers the
// L3/queueing latency that v13's 1 wave/SIMD could not.
__global__ __launch_bounds__(256)
void proj_v14(const float* __restrict__ x, const short* __restrict__ Wb3,
              short* __restrict__ q, short* __restrict__ k, short* __restrict__ vt)
{
    const int t  = threadIdx.x;
    const int l  = t & 63;
    const int cg = t >> 6;               // col-group 0..3 (48 cols each)
    const int l15 = l & 15, g = l >> 4;
    const long row0 = (long)blockIdx.x * 16;

    f32x4 acc0 = {0,0,0,0}, acc1 = {0,0,0,0}, acc2 = {0,0,0,0};

    // A: lane-private frag row = row0+l15, k = s*32 + g*8 + (0..7)
    const float* ax = x + (row0 + l15) * E + g * 8;
    // B: frag fi of col-group cg at step s: Wb3 + ((s*12 + cg*3 + fi)*64 + l)*8
    const short* bp = Wb3 + ((size_t)(cg * 3) * 64 + l) * 8;

    u32x4 xA0, xA1, yA0, yA1, yA2;
    u32x4 xB0, xB1, yB0, yB1, yB2;

#define ISSUE_A(s) do { \
    GLD(xA0, ax + (s) * 32); GLD(xA1, ax + (s) * 32 + 4); \
    GLD(yA0, bp + ((size_t)(s) * 12 + 0) * 512); \
    GLD(yA1, bp + ((size_t)(s) * 12 + 1) * 512); \
    GLD(yA2, bp + ((size_t)(s) * 12 + 2) * 512); \
} while (0)
#define ISSUE_B(s) do { \
    GLD(xB0, ax + (s) * 32); GLD(xB1, ax + (s) * 32 + 4); \
    GLD(yB0, bp + ((size_t)(s) * 12 + 0) * 512); \
    GLD(yB1, bp + ((size_t)(s) * 12 + 1) * 512); \
    GLD(yB2, bp + ((size_t)(s) * 12 + 2) * 512); \
} while (0)
#define COMPUTE(X0, X1, Y0, Y1, Y2) do { \
    bf16x8 af = cvt8u(X0, X1); \
    acc0 = __builtin_amdgcn_mfma_f32_16x16x32_bf16(af, asbf(Y0), acc0, 0, 0, 0); \
    acc1 = __builtin_amdgcn_mfma_f32_16x16x32_bf16(af, asbf(Y1), acc1, 0, 0, 0); \
    acc2 = __builtin_amdgcn_mfma_f32_16x16x32_bf16(af, asbf(Y2), acc2, 0, 0, 0); \
} while (0)

    ISSUE_A(0);
    #pragma unroll 4
    for (int s2 = 0; s2 < 16; ++s2) {
        const int s = 2 * s2;
        // even half: issue s+1 into stage B, wait stage A (s), compute s
        ISSUE_B(s + 1);
        asm volatile("s_waitcnt vmcnt(5)" ::: "memory");
        __builtin_amdgcn_sched_barrier(0);
        COMPUTE(xA0, xA1, yA0, yA1, yA2);
        // odd half: issue s+2 into stage A (if any), wait stage B, compute s+1
        if (s2 < 15) {
            ISSUE_A(s + 2);
            asm volatile("s_waitcnt vmcnt(5)" ::: "memory");
        } else {
            asm volatile("s_waitcnt vmcnt(0)" ::: "memory");
        }
        __builtin_amdgcn_sched_barrier(0);
        COMPUTE(xB0, xB1, yB0, yB1, yB2);
    }
#undef ISSUE_A
#undef ISSUE_B
#undef COMPUTE

    // ---- epilogue: C frag (col=l15, row=g*4+r) ----
    const long trow = row0 + g * 4;
    const long bb   = trow >> 11;
    const int  t0   = (int)(trow & 2047);
    #pragma unroll
    for (int ni = 0; ni < 3; ++ni) {
        const f32x4 acc = (ni == 0) ? acc0 : (ni == 1) ? acc1 : acc2;
        const int n = cg * 48 + ni * 16 + l15;
        const int m = n >> 6;
        const int h = n & 63;
        if (m == 2) {
            short4v pkt;
            #pragma unroll
            for (int r = 0; r < 4; ++r) pkt[r] = f2bf(acc[r]);
            *(short4v*)&vt[(bb * 64 + h) * TT + t0] = pkt;
        } else {
            short* base = (m == 0) ? q : k;
            // fold 1/sqrt(H) AND log2(e) into q -> softmax uses exp2
            const float sc = (m == 0) ? (0.125f * 1.44269504f) : 1.0f;
            #pragma unroll
            for (int r = 0; r < 4; ++r)
                base[(trow + r) * 64 + h] = f2bf(acc[r] * sc);
        }
    }
}

// ---- 32x32 swapped-QK^T flash attention (unchanged) ----
__global__ __launch_bounds__(512)
void attn_v8(const short* __restrict__ qg,
             const short* __restrict__ kg,
             const short* __restrict__ vtg,
             float* __restrict__ out)
{
    __shared__ float Op[8][32][66];
    __shared__ float Ml[8][32][2];

    const int t   = threadIdx.x;
    const int L   = t & 63;
    const int w   = t >> 6;
    const int bid = blockIdx.x;
    const int b   = bid & 7;
    const int pr  = bid >> 3;
    const int l31 = L & 31, hi = L >> 5;

    const int stA = pr, stB = 63 - pr;
    const int nA = stA + 1;
    int WA = (8 * nA + 32) / 65;
    WA = WA < 1 ? 1 : (WA > 7 ? 7 : WA);
    const int WB = 8 - WA;

    const bool isB  = (w >= WA);
    const int  st   = isB ? stB : stA;
    const int  q0   = st * 32;
    const int  strd = isB ? WB : WA;
    const int  c0   = isB ? (w - WA) : w;

    bf16x8 qf[4];
    {
        const short* qp = qg + ((long)b * TT + q0 + l31) * 64 + hi * 8;
        qf[0] = *(const bf16x8*)(qp);
        qf[1] = *(const bf16x8*)(qp + 16);
        qf[2] = *(const bf16x8*)(qp + 32);
        qf[3] = *(const bf16x8*)(qp + 48);
    }

    f32x16 o0 = {}, o1 = {};
    float mrun = -1e30f, lrun = 0.f;

    const short* kbase = kg  + ((long)b * TT + l31) * 64 + hi * 8;
    const short* vbase = vtg + ((long)b * 64 + l31) * TT + hi * 8;

    for (int ci = c0; ci <= st; ci += strd) {
        const int kvs = ci * 32;
        const short* kp = kbase + (long)kvs * 64;
        bf16x8 kf0 = *(const bf16x8*)(kp);
        bf16x8 kf1 = *(const bf16x8*)(kp + 16);
        bf16x8 kf2 = *(const bf16x8*)(kp + 32);
        bf16x8 kf3 = *(const bf16x8*)(kp + 48);
        const short* vp = vbase + kvs;
        bf16x8 vf00 = *(const bf16x8*)(vp);
        bf16x8 vf01 = *(const bf16x8*)(vp + 16);
        bf16x8 vf10 = *(const bf16x8*)(vp + 32 * TT);
        bf16x8 vf11 = *(const bf16x8*)(vp + 32 * TT + 16);

        f32x16 s = {};
        __builtin_amdgcn_s_setprio(1);
        s = __builtin_amdgcn_mfma_f32_32x32x16_bf16(kf0, qf[0], s, 0, 0, 0);
        s = __builtin_amdgcn_mfma_f32_32x32x16_bf16(kf1, qf[1], s, 0, 0, 0);
        s = __builtin_amdgcn_mfma_f32_32x32x16_bf16(kf2, qf[2], s, 0, 0, 0);
        s = __builtin_amdgcn_mfma_f32_32x32x16_bf16(kf3, qf[3], s, 0, 0, 0);
        __builtin_amdgcn_s_setprio(0);

        if (kvs == q0) {
            #pragma unroll
            for (int r = 0; r < 16; ++r) {
                const int crow = (r & 3) + 8 * (r >> 2) + 4 * hi;
                if (crow > l31) s[r] = -1e30f;
            }
        }
        float m01 = fmaxf(s[0], s[1]),   m23 = fmaxf(s[2], s[3]);
        float m45 = fmaxf(s[4], s[5]),   m67 = fmaxf(s[6], s[7]);
        float m89 = fmaxf(s[8], s[9]),   mab = fmaxf(s[10], s[11]);
        float mcd = fmaxf(s[12], s[13]), mef = fmaxf(s[14], s[15]);
        float mloc = fmaxf(fmaxf(fmaxf(m01, m23), fmaxf(m45, m67)),
                           fmaxf(fmaxf(m89, mab), fmaxf(mcd, mef)));
        mloc = fmaxf(mloc, __shfl_xor(mloc, 32));
        if (__any(mloc > mrun + 8.f)) {
            const float mnew = fmaxf(mrun, mloc);
            const float a = fexp2(mrun - mnew);
            mrun = mnew;
            lrun *= a;
            #pragma unroll
            for (int r = 0; r < 16; ++r) { o0[r] *= a; o1[r] *= a; }
        }
        #pragma unroll
        for (int r = 0; r < 16; ++r) s[r] = fexp2(s[r] - mrun);
        {
            float s01 = (s[0] + s[1]) + (s[2] + s[3]);
            float s23 = (s[4] + s[5]) + (s[6] + s[7]);
            float s45 = (s[8] + s[9]) + (s[10] + s[11]);
            float s67 = (s[12] + s[13]) + (s[14] + s[15]);
            float lsum = (s01 + s23) + (s45 + s67);
            lsum += __shfl_xor(lsum, 32);
            lrun += lsum;
        }
        unsigned wv[8];
        #pragma unroll
        for (int i = 0; i < 8; ++i)
            asm("v_cvt_pk_bf16_f32 %0, %1, %2" : "=v"(wv[i]) : "v"(s[2 * i]), "v"(s[2 * i + 1]));
        unsigned p00 = wv[0], p02 = wv[2];
        unsigned p01 = wv[1], p03 = wv[3];
        unsigned p10 = wv[4], p12 = wv[6];
        unsigned p11 = wv[5], p13 = wv[7];
        asm("v_permlane32_swap_b32 %0, %1" : "+v"(p00), "+v"(p02));
        asm("v_permlane32_swap_b32 %0, %1" : "+v"(p01), "+v"(p03));
        asm("v_permlane32_swap_b32 %0, %1" : "+v"(p10), "+v"(p12));
        asm("v_permlane32_swap_b32 %0, %1" : "+v"(p11), "+v"(p13));
        u32x4 pb0u = {p00, p01, p02, p03};
        u32x4 pb1u = {p10, p11, p12, p13};
        bf16x8 pb0, pb1;
        __builtin_memcpy(&pb0, &pb0u, 16);
        __builtin_memcpy(&pb1, &pb1u, 16);
        __builtin_amdgcn_s_setprio(1);
        o0 = __builtin_amdgcn_mfma_f32_32x32x16_bf16(vf00, pb0, o0, 0, 0, 0);
        o0 = __builtin_amdgcn_mfma_f32_32x32x16_bf16(vf01, pb1, o0, 0, 0, 0);
        o1 = __builtin_amdgcn_mfma_f32_32x32x16_bf16(vf10, pb0, o1, 0, 0, 0);
        o1 = __builtin_amdgcn_mfma_f32_32x32x16_bf16(vf11, pb1, o1, 0, 0, 0);
        __builtin_amdgcn_s_setprio(0);
    }

    #pragma unroll
    for (int r = 0; r < 16; ++r) {
        const int h = (r & 3) + 8 * (r >> 2) + 4 * hi;
        Op[w][l31][h]      = o0[r];
        Op[w][l31][32 + h] = o1[r];
    }
    if (hi == 0) {
        Ml[w][l31][0] = mrun;
        Ml[w][l31][1] = lrun;
    }
    __syncthreads();

    {
        const bool tb   = (w >= 4);
        const int  base = tb ? WA : 0;
        const int  cnt  = tb ? WB : WA;
        const long oq0  = (long)(tb ? stB : stA) * 32;
        #pragma unroll
        for (int rr = 0; rr < 8; ++rr) {
            const int row = (w & 3) * 8 + rr;
            float M = -1e30f;
            for (int j = 0; j < cnt; ++j)
                M = fmaxf(M, Ml[base + j][row][0]);
            float Ls = 0.f, val = 0.f;
            for (int j = 0; j < cnt; ++j) {
                const float a = fexp2(Ml[base + j][row][0] - M);
                Ls  += a * Ml[base + j][row][1];
                val += a * Op[base + j][row][L];
            }
            out[((long)b * TT + oq0 + row) * 64 + L] = val / Ls;
        }
    }
}

extern "C" void kernel_launch(void* const* d_in, const int* in_sizes, int n_in,
                              void* d_out, int out_size, void* d_ws, size_t ws_size,
                              hipStream_t stream)
{
    const float* x  = (const float*)d_in[0];
    const float* Wq = (const float*)d_in[1];
    const float* Wk = (const float*)d_in[2];
    const float* Wv = (const float*)d_in[3];
    float* out = (float*)d_out;

    const size_t n = (size_t)BB * TT * H;   // 1,048,576 per tensor
    short* q   = (short*)d_ws;
    short* k   = q + n;
    short* vt  = k + n;                     // V transposed: [B][H][T]
    short* Wb3 = vt + n;                    // 196,608 shorts

    pack_w3  <<<dim3(96),   256, 0, stream>>>(Wq, Wk, Wv, Wb3);
    proj_v14 <<<dim3(1024), 256, 0, stream>>>(x, Wb3, q, k, vt);
    attn_v8  <<<dim3(256),  512, 0, stream>>>(q, k, vt, out);
}

// Round 23
// 51.603 us; speedup vs baseline: 1.4718x; 1.4718x over previous
//
#include <hip/hip_runtime.h>

#define E  1024
#define H  64
#define BB 8
#define TT 2048

typedef __attribute__((ext_vector_type(8)))  short bf16x8;
typedef __attribute__((ext_vector_type(4)))  float f32x4;
typedef __attribute__((ext_vector_type(16))) float f32x16;
typedef __attribute__((ext_vector_type(8)))  short short8;
typedef __attribute__((ext_vector_type(4)))  short short4v;
typedef __attribute__((ext_vector_type(4)))  unsigned u32x4;

__device__ __forceinline__ short f2bf(float f) {
    union { float f; unsigned u; } v; v.f = f;
    unsigned r = v.u + 0x7FFFu + ((v.u >> 16) & 1u);   // RNE
    return (short)(r >> 16);
}

// fast 2^x via the HW transcendental (no HIP __exp2f intrinsic exists)
__device__ __forceinline__ float fexp2(float x) {
    float r;
    asm("v_exp_f32 %0, %1" : "=v"(r) : "v"(x));
    return r;
}

// 8 fp32 -> bf16x8 via 4x v_cvt_pk_bf16_f32
__device__ __forceinline__ bf16x8 cvt8(float4 a0, float4 a1) {
    unsigned w0, w1, w2, w3;
    asm("v_cvt_pk_bf16_f32 %0, %1, %2" : "=v"(w0) : "v"(a0.x), "v"(a0.y));
    asm("v_cvt_pk_bf16_f32 %0, %1, %2" : "=v"(w1) : "v"(a0.z), "v"(a0.w));
    asm("v_cvt_pk_bf16_f32 %0, %1, %2" : "=v"(w2) : "v"(a1.x), "v"(a1.y));
    asm("v_cvt_pk_bf16_f32 %0, %1, %2" : "=v"(w3) : "v"(a1.z), "v"(a1.w));
    u32x4 u = {w0, w1, w2, w3};
    bf16x8 r;
    __builtin_memcpy(&r, &u, 16);
    return r;
}

// ---- pack W into per-K-step, frag-ordered CONTIGUOUS blocks (16x16x32 B) ----
__global__ __launch_bounds__(256)
void pack_w3(const float* __restrict__ Wq, const float* __restrict__ Wk,
             const float* __restrict__ Wv, short* __restrict__ Wb3)
{
    const int t  = blockIdx.x * 256 + threadIdx.x;   // 24576 total
    const int l  = t & 63;
    const int f  = (t >> 6) % 12;
    const int sc = t / 768;                          // s*2+kc, 0..31
    const int n  = f * 16 + (l & 15);
    const int m  = n >> 6, nn = n & 63;
    const float* W = (m == 0) ? Wq : (m == 1 ? Wk : Wv);
    const int k0 = sc * 32 + ((l >> 4) << 3);
    short8 o;
    #pragma unroll
    for (int j = 0; j < 8; ++j) o[j] = f2bf(W[(k0 + j) * 64 + nn]);
    *(short8*)&Wb3[(size_t)t * 8] = o;
}

// ---- proj v10: m97-template GEMM + double-buffered LDS staging ----
// Best measured of 9 structurally distinct proj designs (rounds 9-22).
// Stage s+1 issued into buf^1 BEFORE compute of s from buf; ONE barrier
// per step. 64 KB LDS -> 2 blocks/CU.
__global__ __launch_bounds__(512)
void proj_v10(const float* __restrict__ x, const short* __restrict__ Wb3,
              short* __restrict__ q, short* __restrict__ k, short* __restrict__ vt)
{
    __shared__ float As[2][32 * 64];     // 2 x 8 KB fp32, swizzled 16B units
    __shared__ short Bs[2][1536 * 8];    // 2 x 24 KB bf16, frag-ordered
    const int t = threadIdx.x;
    const int l = t & 63;
    const int w = t >> 6;
    const int wm = w & 1, wn = w >> 1;   // 2 M-groups x 4 N-groups
    const int l15 = l & 15, g = l >> 4;
    const long row0 = (long)blockIdx.x * 32;

    const int arow = wm * 16 + l15;      // A-frag row (lane)
    const int aswz = arow & 7;

    f32x4 acc0 = {0,0,0,0}, acc1 = {0,0,0,0}, acc2 = {0,0,0,0};

    // staging addresses (constant per thread, advance by step)
    const int ar = t >> 4, acu = t & 15;                 // A: unit t
    const float* agp = x + (row0 + ar) * E + ((acu ^ (ar & 7)) << 2);

    // ---- prologue: stage step 0 into buffer 0 ----
    __builtin_amdgcn_global_load_lds(
        (const __attribute__((address_space(1))) void*)(agp),
        (__attribute__((address_space(3))) void*)&As[0][t * 4], 16, 0, 0);
    #pragma unroll
    for (int i = 0; i < 3; ++i) {
        const int u = i * 512 + t;
        __builtin_amdgcn_global_load_lds(
            (const __attribute__((address_space(1))) void*)(Wb3 + (size_t)u * 8),
            (__attribute__((address_space(3))) void*)&Bs[0][u * 8], 16, 0, 0);
    }
    __syncthreads();

    int cur = 0;
    for (int s = 0; s < 16; ++s) {
        // ---- issue stage s+1 into the other buffer BEFORE compute ----
        if (s + 1 < 16) {
            const int nxt = cur ^ 1;
            __builtin_amdgcn_global_load_lds(
                (const __attribute__((address_space(1))) void*)(agp + (s + 1) * 64),
                (__attribute__((address_space(3))) void*)&As[nxt][t * 4], 16, 0, 0);
            const short* gb = Wb3 + (size_t)(s + 1) * 1536 * 8;
            #pragma unroll
            for (int i = 0; i < 3; ++i) {
                const int u = i * 512 + t;
                __builtin_amdgcn_global_load_lds(
                    (const __attribute__((address_space(1))) void*)(gb + (size_t)u * 8),
                    (__attribute__((address_space(3))) void*)&Bs[nxt][u * 8], 16, 0, 0);
            }
        }
        // ---- compute step s from buf cur: 2 kc x 3 nfrags ----
        #pragma unroll
        for (int kc = 0; kc < 2; ++kc) {
            const int cu0 = kc * 8 + g * 2;
            float4 xa = *(const float4*)&As[cur][(arow * 16 + (cu0 ^ aswz)) * 4];
            float4 xb = *(const float4*)&As[cur][(arow * 16 + ((cu0 + 1) ^ aswz)) * 4];
            bf16x8 af = cvt8(xa, xb);
            bf16x8 b0 = *(const bf16x8*)&Bs[cur][((kc * 12 + wn * 3 + 0) * 64 + l) * 8];
            bf16x8 b1 = *(const bf16x8*)&Bs[cur][((kc * 12 + wn * 3 + 1) * 64 + l) * 8];
            bf16x8 b2 = *(const bf16x8*)&Bs[cur][((kc * 12 + wn * 3 + 2) * 64 + l) * 8];
            acc0 = __builtin_amdgcn_mfma_f32_16x16x32_bf16(af, b0, acc0, 0, 0, 0);
            acc1 = __builtin_amdgcn_mfma_f32_16x16x32_bf16(af, b1, acc1, 0, 0, 0);
            acc2 = __builtin_amdgcn_mfma_f32_16x16x32_bf16(af, b2, acc2, 0, 0, 0);
        }
        __syncthreads();   // stage s+1 landed; all reads of buf cur done
        cur ^= 1;
    }

    // ---- epilogue: C frag (col=l15, row=g*4+r) ----
    const long trow = row0 + wm * 16 + g * 4;
    const long bb   = trow >> 11;
    const int  t0   = (int)(trow & 2047);
    #pragma unroll
    for (int ni = 0; ni < 3; ++ni) {
        const f32x4 acc = (ni == 0) ? acc0 : (ni == 1) ? acc1 : acc2;
        const int n = wn * 48 + ni * 16 + l15;
        const int m = n >> 6;
        const int h = n & 63;
        if (m == 2) {
            short4v pkt;
            #pragma unroll
            for (int r = 0; r < 4; ++r) pkt[r] = f2bf(acc[r]);
            *(short4v*)&vt[(bb * 64 + h) * TT + t0] = pkt;
        } else {
            short* base = (m == 0) ? q : k;
            // fold 1/sqrt(H) AND log2(e) into q -> softmax uses exp2
            const float sc = (m == 0) ? (0.125f * 1.44269504f) : 1.0f;
            #pragma unroll
            for (int r = 0; r < 4; ++r)
                base[(trow + r) * 64 + h] = f2bf(acc[r] * sc);
        }
    }
}

// ---- 32x32 swapped-QK^T flash attention ----
__global__ __launch_bounds__(512)
void attn_v8(const short* __restrict__ qg,
             const short* __restrict__ kg,
             const short* __restrict__ vtg,
             float* __restrict__ out)
{
    __shared__ float Op[8][32][66];
    __shared__ float Ml[8][32][2];

    const int t   = threadIdx.x;
    const int L   = t & 63;
    const int w   = t >> 6;
    const int bid = blockIdx.x;
    const int b   = bid & 7;
    const int pr  = bid >> 3;
    const int l31 = L & 31, hi = L >> 5;

    const int stA = pr, stB = 63 - pr;
    const int nA = stA + 1;
    int WA = (8 * nA + 32) / 65;
    WA = WA < 1 ? 1 : (WA > 7 ? 7 : WA);
    const int WB = 8 - WA;

    const bool isB  = (w >= WA);
    const int  st   = isB ? stB : stA;
    const int  q0   = st * 32;
    const int  strd = isB ? WB : WA;
    const int  c0   = isB ? (w - WA) : w;

    bf16x8 qf[4];
    {
        const short* qp = qg + ((long)b * TT + q0 + l31) * 64 + hi * 8;
        qf[0] = *(const bf16x8*)(qp);
        qf[1] = *(const bf16x8*)(qp + 16);
        qf[2] = *(const bf16x8*)(qp + 32);
        qf[3] = *(const bf16x8*)(qp + 48);
    }

    f32x16 o0 = {}, o1 = {};
    float mrun = -1e30f, lrun = 0.f;

    const short* kbase = kg  + ((long)b * TT + l31) * 64 + hi * 8;
    const short* vbase = vtg + ((long)b * 64 + l31) * TT + hi * 8;

    for (int ci = c0; ci <= st; ci += strd) {
        const int kvs = ci * 32;
        const short* kp = kbase + (long)kvs * 64;
        bf16x8 kf0 = *(const bf16x8*)(kp);
        bf16x8 kf1 = *(const bf16x8*)(kp + 16);
        bf16x8 kf2 = *(const bf16x8*)(kp + 32);
        bf16x8 kf3 = *(const bf16x8*)(kp + 48);
        const short* vp = vbase + kvs;
        bf16x8 vf00 = *(const bf16x8*)(vp);
        bf16x8 vf01 = *(const bf16x8*)(vp + 16);
        bf16x8 vf10 = *(const bf16x8*)(vp + 32 * TT);
        bf16x8 vf11 = *(const bf16x8*)(vp + 32 * TT + 16);

        f32x16 s = {};
        __builtin_amdgcn_s_setprio(1);
        s = __builtin_amdgcn_mfma_f32_32x32x16_bf16(kf0, qf[0], s, 0, 0, 0);
        s = __builtin_amdgcn_mfma_f32_32x32x16_bf16(kf1, qf[1], s, 0, 0, 0);
        s = __builtin_amdgcn_mfma_f32_32x32x16_bf16(kf2, qf[2], s, 0, 0, 0);
        s = __builtin_amdgcn_mfma_f32_32x32x16_bf16(kf3, qf[3], s, 0, 0, 0);
        __builtin_amdgcn_s_setprio(0);

        if (kvs == q0) {
            #pragma unroll
            for (int r = 0; r < 16; ++r) {
                const int crow = (r & 3) + 8 * (r >> 2) + 4 * hi;
                if (crow > l31) s[r] = -1e30f;
            }
        }
        float m01 = fmaxf(s[0], s[1]),   m23 = fmaxf(s[2], s[3]);
        float m45 = fmaxf(s[4], s[5]),   m67 = fmaxf(s[6], s[7]);
        float m89 = fmaxf(s[8], s[9]),   mab = fmaxf(s[10], s[11]);
        float mcd = fmaxf(s[12], s[13]), mef = fmaxf(s[14], s[15]);
        float mloc = fmaxf(fmaxf(fmaxf(m01, m23), fmaxf(m45, m67)),
                           fmaxf(fmaxf(m89, mab), fmaxf(mcd, mef)));
        mloc = fmaxf(mloc, __shfl_xor(mloc, 32));
        if (__any(mloc > mrun + 8.f)) {
            const float mnew = fmaxf(mrun, mloc);
            const float a = fexp2(mrun - mnew);
            mrun = mnew;
            lrun *= a;
            #pragma unroll
            for (int r = 0; r < 16; ++r) { o0[r] *= a; o1[r] *= a; }
        }
        #pragma unroll
        for (int r = 0; r < 16; ++r) s[r] = fexp2(s[r] - mrun);
        {
            float s01 = (s[0] + s[1]) + (s[2] + s[3]);
            float s23 = (s[4] + s[5]) + (s[6] + s[7]);
            float s45 = (s[8] + s[9]) + (s[10] + s[11]);
            float s67 = (s[12] + s[13]) + (s[14] + s[15]);
            float lsum = (s01 + s23) + (s45 + s67);
            lsum += __shfl_xor(lsum, 32);
            lrun += lsum;
        }
        unsigned wv[8];
        #pragma unroll
        for (int i = 0; i < 8; ++i)
            asm("v_cvt_pk_bf16_f32 %0, %1, %2" : "=v"(wv[i]) : "v"(s[2 * i]), "v"(s[2 * i + 1]));
        unsigned p00 = wv[0], p02 = wv[2];
        unsigned p01 = wv[1], p03 = wv[3];
        unsigned p10 = wv[4], p12 = wv[6];
        unsigned p11 = wv[5], p13 = wv[7];
        asm("v_permlane32_swap_b32 %0, %1" : "+v"(p00), "+v"(p02));
        asm("v_permlane32_swap_b32 %0, %1" : "+v"(p01), "+v"(p03));
        asm("v_permlane32_swap_b32 %0, %1" : "+v"(p10), "+v"(p12));
        asm("v_permlane32_swap_b32 %0, %1" : "+v"(p11), "+v"(p13));
        u32x4 pb0u = {p00, p01, p02, p03};
        u32x4 pb1u = {p10, p11, p12, p13};
        bf16x8 pb0, pb1;
        __builtin_memcpy(&pb0, &pb0u, 16);
        __builtin_memcpy(&pb1, &pb1u, 16);
        __builtin_amdgcn_s_setprio(1);
        o0 = __builtin_amdgcn_mfma_f32_32x32x16_bf16(vf00, pb0, o0, 0, 0, 0);
        o0 = __builtin_amdgcn_mfma_f32_32x32x16_bf16(vf01, pb1, o0, 0, 0, 0);
        o1 = __builtin_amdgcn_mfma_f32_32x32x16_bf16(vf10, pb0, o1, 0, 0, 0);
        o1 = __builtin_amdgcn_mfma_f32_32x32x16_bf16(vf11, pb1, o1, 0, 0, 0);
        __builtin_amdgcn_s_setprio(0);
    }

    #pragma unroll
    for (int r = 0; r < 16; ++r) {
        const int h = (r & 3) + 8 * (r >> 2) + 4 * hi;
        Op[w][l31][h]      = o0[r];
        Op[w][l31][32 + h] = o1[r];
    }
    if (hi == 0) {
        Ml[w][l31][0] = mrun;
        Ml[w][l31][1] = lrun;
    }
    __syncthreads();

    {
        const bool tb   = (w >= 4);
        const int  base = tb ? WA : 0;
        const int  cnt  = tb ? WB : WA;
        const long oq0  = (long)(tb ? stB : stA) * 32;
        #pragma unroll
        for (int rr = 0; rr < 8; ++rr) {
            const int row = (w & 3) * 8 + rr;
            float M = -1e30f;
            for (int j = 0; j < cnt; ++j)
                M = fmaxf(M, Ml[base + j][row][0]);
            float Ls = 0.f, val = 0.f;
            for (int j = 0; j < cnt; ++j) {
                const float a = fexp2(Ml[base + j][row][0] - M);
                Ls  += a * Ml[base + j][row][1];
                val += a * Op[base + j][row][L];
            }
            out[((long)b * TT + oq0 + row) * 64 + L] = val / Ls;
        }
    }
}

extern "C" void kernel_launch(void* const* d_in, const int* in_sizes, int n_in,
                              void* d_out, int out_size, void* d_ws, size_t ws_size,
                              hipStream_t stream)
{
    const float* x  = (const float*)d_in[0];
    const float* Wq = (const float*)d_in[1];
    const float* Wk = (const float*)d_in[2];
    const float* Wv = (const float*)d_in[3];
    float* out = (float*)d_out;

    const size_t n = (size_t)BB * TT * H;   // 1,048,576 per tensor
    short* q   = (short*)d_ws;
    short* k   = q + n;
    short* vt  = k + n;                     // V transposed: [B][H][T]
    short* Wb3 = vt + n;                    // 196,608 shorts

    pack_w3  <<<dim3(96),  256, 0, stream>>>(Wq, Wk, Wv, Wb3);
    proj_v10 <<<dim3(512), 512, 0, stream>>>(x, Wb3, q, k, vt);
    attn_v8  <<<dim3(256), 512, 0, stream>>>(q, k, vt, out);
}